// Round 11
// baseline (1201.498 us; speedup 1.0000x reference)
//
#include <hip/hip_runtime.h>
#include <cstddef>
#include <cstdint>
#include <math.h>

#define BB   4
#define TT   2048
#define CCH  1024
#define HH   16
#define DD   64
#define CSZ  16
#define NTC  128
#define EPSF 1e-5f
#define WVS  8
#define STR  3072   // qkv row stride (u32): q[0,1024) k[1024,2048) v[2048,3072)

typedef __attribute__((ext_vector_type(8))) short bf16x8;
typedef __attribute__((ext_vector_type(4))) float f32x4;
typedef __attribute__((ext_vector_type(2))) float f32x2;

// Barrier that flushes LDS ops only. Global stores / register prefetch loads stay
// in flight across the barrier (guide T4); compiler still inserts vmcnt(N) before
// each use of a prefetched register.
__device__ __forceinline__ void bar_lds() {
  asm volatile("s_waitcnt lgkmcnt(0)" ::: "memory");
  __builtin_amdgcn_s_barrier();
}

// ---------- split-float helpers: f32 ≈ hi(bf16) + lo(bf16), packed (hi | lo<<16) ----------
__device__ __forceinline__ uint32_t pack_split(float f) {
  uint32_t b = __float_as_uint(f);
  uint32_t uh = (b + 0x7fffu + ((b >> 16) & 1u)) >> 16;   // RNE bf16 of f
  float fh = __uint_as_float(uh << 16);
  float r = f - fh;
  return uh | (__float_as_uint(r) & 0xffff0000u);          // lo = trunc bf16 of residual
}
__device__ __forceinline__ float unpack_f(uint32_t u) {
  return __uint_as_float(u << 16) + __uint_as_float(u & 0xffff0000u);
}

// Wave64 sum via DPP (VALU pipe).
__device__ __forceinline__ float wave_sum(float x) {
  float v = x;
  v += __int_as_float(__builtin_amdgcn_update_dpp(0, __float_as_int(v), 0x111, 0xf, 0xf, true));
  v += __int_as_float(__builtin_amdgcn_update_dpp(0, __float_as_int(v), 0x112, 0xf, 0xf, true));
  v += __int_as_float(__builtin_amdgcn_update_dpp(0, __float_as_int(v), 0x114, 0xf, 0xf, true));
  v += __int_as_float(__builtin_amdgcn_update_dpp(0, __float_as_int(v), 0x118, 0xf, 0xf, true));
  v += __int_as_float(__builtin_amdgcn_update_dpp(0, __float_as_int(v), 0x142, 0xa, 0xf, true));
  v += __int_as_float(__builtin_amdgcn_update_dpp(0, __float_as_int(v), 0x143, 0xc, 0xf, true));
  return __int_as_float(__builtin_amdgcn_readlane(__float_as_int(v), 63));
}

// Sum across a 16-lane group: quad_perm xor1, xor2, row_ror:4, row_ror:8.
__device__ __forceinline__ float red16(float x) {
  float v = x;
  v += __int_as_float(__builtin_amdgcn_update_dpp(0, __float_as_int(v), 0x0B1, 0xf, 0xf, true));
  v += __int_as_float(__builtin_amdgcn_update_dpp(0, __float_as_int(v), 0x04E, 0xf, 0xf, true));
  v += __int_as_float(__builtin_amdgcn_update_dpp(0, __float_as_int(v), 0x124, 0xf, 0xf, true));
  v += __int_as_float(__builtin_amdgcn_update_dpp(0, __float_as_int(v), 0x128, 0xf, 0xf, true));
  return v;
}

__device__ __forceinline__ float sigmoidf_(float x) {
  return 1.f / (1.f + expf(-x));
}

// ---------- pre-split x: f32 -> hi/lo ushort planes (one-time, memory-bound) ----------
__global__ __launch_bounds__(256) void presplit_x(
    const float* __restrict__ x, unsigned short* __restrict__ xhi,
    unsigned short* __restrict__ xlo, int n4) {
  const int i = blockIdx.x * 256 + threadIdx.x;
  if (i >= n4) return;
  float4 f = *(const float4*)(x + (size_t)i * 4);
  uint32_t p0 = pack_split(f.x), p1 = pack_split(f.y);
  uint32_t p2 = pack_split(f.z), p3 = pack_split(f.w);
  ushort4 h, lo;
  h.x = (unsigned short)(p0 & 0xffffu);  lo.x = (unsigned short)(p0 >> 16);
  h.y = (unsigned short)(p1 & 0xffffu);  lo.y = (unsigned short)(p1 >> 16);
  h.z = (unsigned short)(p2 & 0xffffu);  lo.z = (unsigned short)(p2 >> 16);
  h.w = (unsigned short)(p3 & 0xffffu);  lo.w = (unsigned short)(p3 >> 16);
  *(ushort4*)(xhi + (size_t)i * 4) = h;
  *(ushort4*)(xlo + (size_t)i * 4) = lo;
}

// ---------- transpose + split into PLANES: W (KxN f32) -> Whi/Wlo rows [rowOff, rowOff+N) ----------
__global__ __launch_bounds__(256) void split_transpose_pl(
    const float* __restrict__ W, unsigned short* __restrict__ Whi,
    unsigned short* __restrict__ Wlo, int K, int N, int rowOff) {
  __shared__ float t[32][33];
  const int n0 = blockIdx.x * 32, k0 = blockIdx.y * 32;
  const int tx = threadIdx.x & 31, ty = threadIdx.x >> 5;  // ty 0..7
#pragma unroll
  for (int i = 0; i < 4; i++) {
    int n = n0 + tx;
    t[ty + i * 8][tx] = (n < N) ? W[(size_t)(k0 + ty + i * 8) * N + n] : 0.f;
  }
  __syncthreads();
#pragma unroll
  for (int i = 0; i < 4; i++) {
    int n = n0 + ty + i * 8;
    if (n < N) {
      uint32_t ps = pack_split(t[tx][ty + i * 8]);
      size_t off = (size_t)(rowOff + n) * K + k0 + tx;
      Whi[off] = (unsigned short)(ps & 0xffffu);
      Wlo[off] = (unsigned short)(ps >> 16);
    }
  }
}

// ---------- split-bf16 MFMA GEMM: C = A @ B^T + bias ----------
// BOTH operands arrive as hi/lo ushort planes -> staging is pure uint4 copies
// (zero VALU transform in the K-loop). B rows >= Nb are zero-staged; stores
// guarded to col < Ns; cols >= pc0 go raw f32 to Pbuf (ld 48).
// NORM: blocks with col0 < 2048 L2-normalize each 64-col head-row before packing.
// Register prefetch + lgkm-only barriers: vmem spans the K-loop barriers.
template<bool C_PACKED, bool NORM>
__global__ __launch_bounds__(256) void gemm_split(
    const unsigned short* __restrict__ Ahg,
    const unsigned short* __restrict__ Alg, int lda,
    const unsigned short* __restrict__ Bhg,
    const unsigned short* __restrict__ Blg,
    const float* __restrict__ bias,
    void* __restrict__ Cv, float* __restrict__ Pbuf,
    int M, int ldc, int K, int Nb, int Ns, int pc0) {
  __shared__ unsigned short Ahi[128][40];
  __shared__ unsigned short Alo[128][40];
  __shared__ unsigned short Bhi[128][40];
  __shared__ unsigned short Blo[128][40];

  const int tid = threadIdx.x;
  const int row0 = blockIdx.y * 128;
  const int col0 = blockIdx.x * 128;
  const int wv = tid >> 6;
  const int l  = tid & 63;
  const int wr = wv >> 1, wc = wv & 1;
  const int lrow = l & 15;
  const int kgrp = (l >> 4) * 8;

  const int sr = tid >> 1;
  const int sk = (tid & 1) * 16;

  f32x4 acc[4][4];
#pragma unroll
  for (int i = 0; i < 4; i++)
#pragma unroll
    for (int j = 0; j < 4; j++) acc[i][j] = (f32x4){0.f, 0.f, 0.f, 0.f};

  uint4 pah[2], pal[2];   // A planes: 32B hi + 32B lo
  uint4 pbh[2], pbl[2];   // B planes

  auto load_tile = [&](int k0) {
    const unsigned short* ah = Ahg + (size_t)(row0 + sr) * lda + k0 + sk;
    const unsigned short* al = Alg + (size_t)(row0 + sr) * lda + k0 + sk;
    pah[0] = *(const uint4*)ah;  pah[1] = *(const uint4*)(ah + 8);
    pal[0] = *(const uint4*)al;  pal[1] = *(const uint4*)(al + 8);
    if (col0 + sr < Nb) {
      const unsigned short* bh = Bhg + (size_t)(col0 + sr) * K + k0 + sk;
      const unsigned short* bl = Blg + (size_t)(col0 + sr) * K + k0 + sk;
      pbh[0] = *(const uint4*)bh;  pbh[1] = *(const uint4*)(bh + 8);
      pbl[0] = *(const uint4*)bl;  pbl[1] = *(const uint4*)(bl + 8);
    } else {
      pbh[0] = pbh[1] = pbl[0] = pbl[1] = make_uint4(0u, 0u, 0u, 0u);
    }
  };

  auto commit_tile = [&]() {
    *(uint4*)&Ahi[sr][sk]     = pah[0];
    *(uint4*)&Ahi[sr][sk + 8] = pah[1];
    *(uint4*)&Alo[sr][sk]     = pal[0];
    *(uint4*)&Alo[sr][sk + 8] = pal[1];
    *(uint4*)&Bhi[sr][sk]     = pbh[0];
    *(uint4*)&Bhi[sr][sk + 8] = pbh[1];
    *(uint4*)&Blo[sr][sk]     = pbl[0];
    *(uint4*)&Blo[sr][sk + 8] = pbl[1];
  };

  load_tile(0);
  for (int k0 = 0; k0 < K; k0 += 32) {
    commit_tile();
    bar_lds();                               // flush ds_writes; vmem stays in flight
    if (k0 + 32 < K) load_tile(k0 + 32);     // spans the next barrier

    bf16x8 bh[4], bl[4];
#pragma unroll
    for (int j = 0; j < 4; j++) {
      bh[j] = *(const bf16x8*)&Bhi[wc * 64 + j * 16 + lrow][kgrp];
      bl[j] = *(const bf16x8*)&Blo[wc * 64 + j * 16 + lrow][kgrp];
    }
#pragma unroll
    for (int i = 0; i < 4; i++) {
      bf16x8 ah = *(const bf16x8*)&Ahi[wr * 64 + i * 16 + lrow][kgrp];
      bf16x8 al = *(const bf16x8*)&Alo[wr * 64 + i * 16 + lrow][kgrp];
#pragma unroll
      for (int j = 0; j < 4; j++) {
        acc[i][j] = __builtin_amdgcn_mfma_f32_16x16x32_bf16(ah, bh[j], acc[i][j], 0, 0, 0);
        acc[i][j] = __builtin_amdgcn_mfma_f32_16x16x32_bf16(ah, bl[j], acc[i][j], 0, 0, 0);
        acc[i][j] = __builtin_amdgcn_mfma_f32_16x16x32_bf16(al, bh[j], acc[i][j], 0, 0, 0);
      }
    }
    bar_lds();
  }

  // ---- epilogue: C/D layout col=lane&15, row=(lane>>4)*4+reg ----
  const int crow4 = (l >> 4) * 4;
  if (NORM && col0 < 2048) {
    // q/k rows: normalize each head-row (64 cols) in-register.
    float bj[4];
#pragma unroll
    for (int j = 0; j < 4; j++) bj[j] = bias[col0 + wc * 64 + j * 16 + lrow];
#pragma unroll
    for (int i = 0; i < 4; i++) {
#pragma unroll
      for (int r = 0; r < 4; r++) {
        float vals[4];
        float ss = 0.f;
#pragma unroll
        for (int j = 0; j < 4; j++) {
          vals[j] = acc[i][j][r] + bj[j];
          ss += vals[j] * vals[j];
        }
        ss = red16(ss);
        float sc = 1.f / fmaxf(sqrtf(ss), 1e-12f);
        const int rowb = row0 + wr * 64 + i * 16 + crow4 + r;
#pragma unroll
        for (int j = 0; j < 4; j++) {
          const int col = col0 + wc * 64 + j * 16 + lrow;
          ((uint32_t*)Cv)[(size_t)rowb * ldc + col] = pack_split(vals[j] * sc);
        }
      }
    }
  } else {
#pragma unroll
    for (int i = 0; i < 4; i++) {
#pragma unroll
      for (int j = 0; j < 4; j++) {
        const int col = col0 + wc * 64 + j * 16 + lrow;
        const float bv = (col < Ns) ? bias[col] : 0.f;
        const int rowb = row0 + wr * 64 + i * 16 + crow4;
#pragma unroll
        for (int r = 0; r < 4; r++) {
          float v = acc[i][j][r] + bv;
          if (col < Ns) {
            if (col >= pc0) {
              Pbuf[(size_t)(rowb + r) * 48 + (col - pc0)] = v;          // raw f32 params
            } else if (C_PACKED) {
              ((uint32_t*)Cv)[(size_t)(rowb + r) * ldc + col] = pack_split(v);
            } else {
              ((float*)Cv)[(size_t)(rowb + r) * ldc + col] = v;
            }
          }
        }
      }
    }
  }
}

// Titans recurrence (proven structure, ~540 µs). One block per (b,h), 512 threads
// = 8 waves x 8 S-rows; packed-fp32 (pk_fma) hot loops; lgkm-only barriers. q/k
// arrive L2-normalized; p compact (M x 48 f32). LN(o) is written as hi/lo ushort
// PLANES (2 coalesced short-stores, fire-and-forget) so the proj GEMM's A-staging
// is pure copies.
__global__ __launch_bounds__(512) void titans_rec(
    const uint32_t* __restrict__ qkv, const float* __restrict__ p,
    unsigned short* __restrict__ ohi, unsigned short* __restrict__ olo,
    const float* __restrict__ w, const float* __restrict__ bparm) {
  const int bh = blockIdx.x;
  const int b = bh >> 4;
  const int h = bh & 15;
  const int tid = threadIdx.x;
  const int wv = tid >> 6;   // 0..7
  const int l = tid & 63;

  __shared__ float k_s[2][CSZ][DD];
  __shared__ float q_s[2][CSZ][DD];
  __shared__ float v_s[CSZ][DD];
  __shared__ float dkh_s[CSZ][DD];
  __shared__ float part[2][WVS][CSZ][DD];
  __shared__ float4 prm_s[2][CSZ];

  f32x2 S2[4], M2[4];
#pragma unroll
  for (int r = 0; r < 4; r++) { S2[r] = (f32x2){0.f, 0.f}; M2[r] = (f32x2){0.f, 0.f}; }

  const float w_l = w[h * DD + l];
  const float b_l = bparm[h * DD + l];

  const uint32_t* qbase = qkv + (size_t)(b * TT) * STR + h * DD;
  const float* pbase = p + (size_t)(b * TT) * 48 + h * 3;
  unsigned short* ohbase = ohi + (size_t)(b * TT) * CCH + h * DD;
  unsigned short* olbase = olo + (size_t)(b * TT) * CCH + h * DD;

  uint32_t rq[2], rk[2], rv[2];
  float rp0 = 0.f, rp1 = 0.f, rp2 = 0.f;
  // ---- prologue: load + commit chunk 0; load chunk 1 into regs ----
  {
#pragma unroll
    for (int i = 0; i < 2; i++) {
      const int row = wv + i * 8;
      size_t roff = (size_t)row * STR + l;
      q_s[0][row][l] = unpack_f(qbase[roff]);
      k_s[0][row][l] = unpack_f(qbase[roff + 1024]);
      v_s[row][l]    = unpack_f(qbase[roff + 2048]);
    }
    if (tid < CSZ) {
      const float* pp = pbase + (size_t)tid * 48;
      prm_s[0][tid] = make_float4(sigmoidf_(pp[0]), sigmoidf_(pp[1]), sigmoidf_(pp[2]), 0.f);
    }
#pragma unroll
    for (int i = 0; i < 2; i++) {
      size_t roff = (size_t)(CSZ + wv + i * 8) * STR + l;
      rq[i] = qbase[roff];
      rk[i] = qbase[roff + 1024];
      rv[i] = qbase[roff + 2048];
    }
    if (tid < CSZ) {
      const float* pp = pbase + (size_t)(CSZ + tid) * 48;
      rp0 = pp[0]; rp1 = pp[1]; rp2 = pp[2];
    }
  }
  bar_lds();

  for (int nt = 0; nt < NTC; nt++) {
    const int buf = nt & 1;
    float (*partw)[CSZ][DD] = part[buf];       // this chunk's kh, then po
    float (*partr)[CSZ][DD] = part[buf ^ 1];   // previous chunk's po

    // ---- phase A: deferred o/LN/store of chunk nt-1, then kh partials (packed) ----
    if (nt > 0) {
#pragma unroll
      for (int i = 0; i < 2; i++) {
        const int t = wv + i * 8;
        float o = 0.f;
#pragma unroll
        for (int ww = 0; ww < WVS; ww++) o += partr[ww][t][l];
        float mu = wave_sum(o) * (1.f / 64.f);
        float xc = o - mu;
        float var = wave_sum(xc * xc) * (1.f / 64.f);
        float rstd = rsqrtf(var + EPSF);
        float y = xc * rstd * w_l + b_l;
        uint32_t ps = pack_split(y);
        size_t ooff = (size_t)((nt - 1) * CSZ + t) * CCH + l;
        ohbase[ooff] = (unsigned short)(ps & 0xffffu);
        olbase[ooff] = (unsigned short)(ps >> 16);
      }
    }
#pragma unroll
    for (int c = 0; c < CSZ; c++) {
      const f32x2* kp2 = (const f32x2*)&k_s[buf][c][wv * 8];
      f32x2 a2;
      a2 = kp2[0] * S2[0];
      a2 = kp2[1] * S2[1] + a2;
      a2 = kp2[2] * S2[2] + a2;
      a2 = kp2[3] * S2[3] + a2;
      partw[wv][c][l] = a2.x + a2.y;
    }
    bar_lds();

    // ---- phase B: LN fwd + bwd — two token rows per wave ----
#pragma unroll
    for (int i = 0; i < 2; i++) {
      const int c = wv + i * 8;
      float kh = 0.f;
#pragma unroll
      for (int ww = 0; ww < WVS; ww++) kh += partw[ww][c][l];
      float mu = wave_sum(kh) * (1.f / 64.f);
      float xc = kh - mu;
      float var = wave_sum(xc * xc) * (1.f / 64.f);
      float rstd = rsqrtf(var + EPSF);
      float xhat = xc * rstd;
      float y = xhat * w_l + b_l;
      float dy = 2.f * (y - v_s[c][l]);
      float wdy = dy * w_l;
      float c1 = wave_sum(xhat * wdy) * (1.f / 64.f);
      float c2 = wave_sum(wdy) * (1.f / 64.f);
      dkh_s[c][l] = (wdy - xhat * c1 - c2) * rstd;
    }
    bar_lds();

    // ---- phase C: commit next tiles, issue prefetch, token scan (packed) ----
    if (nt + 1 < NTC) {
#pragma unroll
      for (int i = 0; i < 2; i++) {
        const int row = wv + i * 8;
        k_s[buf ^ 1][row][l] = unpack_f(rk[i]);
        q_s[buf ^ 1][row][l] = unpack_f(rq[i]);
        v_s[row][l] = unpack_f(rv[i]);
      }
      if (tid < CSZ)
        prm_s[buf ^ 1][tid] = make_float4(sigmoidf_(rp0), sigmoidf_(rp1), sigmoidf_(rp2), 0.f);
    }
    if (nt + 2 < NTC) {
#pragma unroll
      for (int i = 0; i < 2; i++) {
        size_t roff = (size_t)((nt + 2) * CSZ + wv + i * 8) * STR + l;
        rq[i] = qbase[roff];
        rk[i] = qbase[roff + 1024];
        rv[i] = qbase[roff + 2048];
      }
      if (tid < CSZ) {
        const float* pp = pbase + (size_t)((nt + 2) * CSZ + tid) * 48;
        rp0 = pp[0]; rp1 = pp[1]; rp2 = pp[2];
      }
    }
#pragma unroll
    for (int t = 0; t < CSZ; t++) {
      float4 prm = prm_s[buf][t];
      float a = prm.x * dkh_s[t][l];
      const f32x2 na2 = (f32x2){-a, -a};
      const f32x2 et2 = (f32x2){prm.z, prm.z};
      const f32x2 be2 = (f32x2){1.f - prm.y, 1.f - prm.y};
      const f32x2* kp2 = (const f32x2*)&k_s[buf][t][wv * 8];
      const f32x2* qp2 = (const f32x2*)&q_s[buf][t][wv * 8];
      f32x2 po2 = (f32x2){0.f, 0.f};
#pragma unroll
      for (int pq = 0; pq < 4; pq++) {
        M2[pq] = et2 * M2[pq] + na2 * kp2[pq];   // pk_mul + pk_fma
        S2[pq] = be2 * S2[pq] + M2[pq];          // pk_fma
        po2    = qp2[pq] * S2[pq] + po2;         // pk_fma
      }
      partw[wv][t][l] = po2.x + po2.y;
    }
    bar_lds();
  }

  // ---- epilogue: deferred D for the last chunk ----
  {
    float (*partr)[CSZ][DD] = part[(NTC - 1) & 1];
#pragma unroll
    for (int i = 0; i < 2; i++) {
      const int t = wv + i * 8;
      float o = 0.f;
#pragma unroll
      for (int ww = 0; ww < WVS; ww++) o += partr[ww][t][l];
      float mu = wave_sum(o) * (1.f / 64.f);
      float xc = o - mu;
      float var = wave_sum(xc * xc) * (1.f / 64.f);
      float rstd = rsqrtf(var + EPSF);
      float y = xc * rstd * w_l + b_l;
      uint32_t ps = pack_split(y);
      size_t ooff = (size_t)((NTC - 1) * CSZ + t) * CCH + l;
      ohbase[ooff] = (unsigned short)(ps & 0xffffu);
      olbase[ooff] = (unsigned short)(ps >> 16);
    }
  }
}

extern "C" void kernel_launch(void* const* d_in, const int* in_sizes, int n_in,
                              void* d_out, int out_size, void* d_ws, size_t ws_size,
                              hipStream_t stream) {
  const float* x      = (const float*)d_in[0];
  const float* W_attn = (const float*)d_in[1];
  const float* b_attn = (const float*)d_in[2];
  const float* W_parm = (const float*)d_in[3];
  const float* b_parm = (const float*)d_in[4];
  const float* W_proj = (const float*)d_in[5];
  const float* b_proj = (const float*)d_in[6];
  const float* w      = (const float*)d_in[7];
  const float* bb     = (const float*)d_in[8];
  float* out = (float*)d_out;

  const int M = BB * TT;        // 8192
  uint32_t* qkv = (uint32_t*)d_ws;                           // M x 3072 packed u32
  float* pbf = (float*)(qkv + (size_t)M * STR);              // M x 48 f32
  unsigned short* xop_hi = (unsigned short*)(pbf + (size_t)M * 48);  // M x 1024 (x planes; reused as o planes)
  unsigned short* xop_lo = xop_hi + (size_t)M * CCH;
  unsigned short* wattn_hi = xop_lo + (size_t)M * CCH;               // 3120 x 1024
  unsigned short* wattn_lo = wattn_hi + (size_t)3120 * 1024;
  unsigned short* wproj_hi = wattn_lo + (size_t)3120 * 1024;         // 1024 x 1024
  unsigned short* wproj_lo = wproj_hi + (size_t)1024 * 1024;
  float* bcat = (float*)(wproj_lo + (size_t)1024 * 1024);            // 3120 f32

  hipMemcpyAsync(bcat, b_attn, 3072 * sizeof(float), hipMemcpyDeviceToDevice, stream);
  hipMemcpyAsync(bcat + 3072, b_parm, 48 * sizeof(float), hipMemcpyDeviceToDevice, stream);

  // one-time pre-splits (memory-bound)
  presplit_x<<<(M * CCH / 4 + 255) / 256, 256, 0, stream>>>(x, xop_hi, xop_lo, M * CCH / 4);
  split_transpose_pl<<<dim3(3072 / 32, 1024 / 32), 256, 0, stream>>>(W_attn, wattn_hi, wattn_lo, 1024, 3072, 0);
  split_transpose_pl<<<dim3(2, 1024 / 32), 256, 0, stream>>>(W_parm, wattn_hi, wattn_lo, 1024, 48, 3072);
  split_transpose_pl<<<dim3(1024 / 32, 1024 / 32), 256, 0, stream>>>(W_proj, wproj_hi, wproj_lo, 1024, 1024, 0);

  // fused: [qkv | p] = x @ [W_attn | W_param] + bias; q/k L2-normalized in-epilogue;
  // q/k/v packed into qkv, p raw f32 into pbf. A = x planes (pure-copy staging).
  gemm_split<true, true><<<dim3(25, M / 128), 256, 0, stream>>>(
      xop_hi, xop_lo, CCH, wattn_hi, wattn_lo, bcat, qkv, pbf, M, STR, CCH,
      /*Nb=*/3120, /*Ns=*/3120, /*pc0=*/3072);
  // recurrence; writes LN(o) as hi/lo planes over the (dead) x planes
  titans_rec<<<BB * HH, 512, 0, stream>>>(qkv, pbf, xop_hi, xop_lo, w, bb);
  // out = o @ W_proj + b_proj. A = o planes (pure-copy staging).
  gemm_split<false, false><<<dim3(CCH / 128, M / 128), 256, 0, stream>>>(
      xop_hi, xop_lo, CCH, wproj_hi, wproj_lo, b_proj, out, nullptr, M, CCH, CCH,
      /*Nb=*/1024, /*Ns=*/1024, /*pc0=*/1 << 30);
}

// Round 12
// 908.672 us; speedup vs baseline: 1.3223x; 1.3223x over previous
//
#include <hip/hip_runtime.h>
#include <cstddef>
#include <cstdint>
#include <math.h>

#define BB   4
#define TT   2048
#define CCH  1024
#define HH   16
#define DD   64
#define CSZ  16
#define NTC  128
#define EPSF 1e-5f
#define WVS  8
#define STR  3072   // qkv row stride (u32): q[0,1024) k[1024,2048) v[2048,3072); p separate

typedef __attribute__((ext_vector_type(8))) short bf16x8;
typedef __attribute__((ext_vector_type(4))) float f32x4;
typedef __attribute__((ext_vector_type(2))) float f32x2;

// Barrier that flushes LDS ops only. Global stores / register prefetch loads stay
// in flight across the barrier (guide T4); compiler still inserts vmcnt(N) before
// each use of a prefetched register.
__device__ __forceinline__ void bar_lds() {
  asm volatile("s_waitcnt lgkmcnt(0)" ::: "memory");
  __builtin_amdgcn_s_barrier();
}

// ---------- split-float helpers: f32 ≈ hi(bf16) + lo(bf16), packed (hi | lo<<16) ----------
__device__ __forceinline__ uint32_t pack_split(float f) {
  uint32_t b = __float_as_uint(f);
  uint32_t uh = (b + 0x7fffu + ((b >> 16) & 1u)) >> 16;   // RNE bf16 of f
  float fh = __uint_as_float(uh << 16);
  float r = f - fh;
  return uh | (__float_as_uint(r) & 0xffff0000u);          // lo = trunc bf16 of residual
}
__device__ __forceinline__ float unpack_f(uint32_t u) {
  return __uint_as_float(u << 16) + __uint_as_float(u & 0xffff0000u);
}

// Wave64 sum via DPP (VALU pipe).
__device__ __forceinline__ float wave_sum(float x) {
  float v = x;
  v += __int_as_float(__builtin_amdgcn_update_dpp(0, __float_as_int(v), 0x111, 0xf, 0xf, true));
  v += __int_as_float(__builtin_amdgcn_update_dpp(0, __float_as_int(v), 0x112, 0xf, 0xf, true));
  v += __int_as_float(__builtin_amdgcn_update_dpp(0, __float_as_int(v), 0x114, 0xf, 0xf, true));
  v += __int_as_float(__builtin_amdgcn_update_dpp(0, __float_as_int(v), 0x118, 0xf, 0xf, true));
  v += __int_as_float(__builtin_amdgcn_update_dpp(0, __float_as_int(v), 0x142, 0xa, 0xf, true));
  v += __int_as_float(__builtin_amdgcn_update_dpp(0, __float_as_int(v), 0x143, 0xc, 0xf, true));
  return __int_as_float(__builtin_amdgcn_readlane(__float_as_int(v), 63));
}

// Sum across a 16-lane group: quad_perm xor1, xor2, row_ror:4, row_ror:8.
__device__ __forceinline__ float red16(float x) {
  float v = x;
  v += __int_as_float(__builtin_amdgcn_update_dpp(0, __float_as_int(v), 0x0B1, 0xf, 0xf, true));
  v += __int_as_float(__builtin_amdgcn_update_dpp(0, __float_as_int(v), 0x04E, 0xf, 0xf, true));
  v += __int_as_float(__builtin_amdgcn_update_dpp(0, __float_as_int(v), 0x124, 0xf, 0xf, true));
  v += __int_as_float(__builtin_amdgcn_update_dpp(0, __float_as_int(v), 0x128, 0xf, 0xf, true));
  return v;
}

__device__ __forceinline__ float sigmoidf_(float x) {
  return 1.f / (1.f + expf(-x));
}

// ---------- transpose + split into PLANES: W (KxN f32) -> Whi/Wlo rows [rowOff, rowOff+N) ----------
__global__ __launch_bounds__(256) void split_transpose_pl(
    const float* __restrict__ W, unsigned short* __restrict__ Whi,
    unsigned short* __restrict__ Wlo, int K, int N, int rowOff) {
  __shared__ float t[32][33];
  const int n0 = blockIdx.x * 32, k0 = blockIdx.y * 32;
  const int tx = threadIdx.x & 31, ty = threadIdx.x >> 5;  // ty 0..7
#pragma unroll
  for (int i = 0; i < 4; i++) {
    int n = n0 + tx;
    t[ty + i * 8][tx] = (n < N) ? W[(size_t)(k0 + ty + i * 8) * N + n] : 0.f;
  }
  __syncthreads();
#pragma unroll
  for (int i = 0; i < 4; i++) {
    int n = n0 + ty + i * 8;
    if (n < N) {
      uint32_t ps = pack_split(t[tx][ty + i * 8]);
      size_t off = (size_t)(rowOff + n) * K + k0 + tx;
      Whi[off] = (unsigned short)(ps & 0xffffu);
      Wlo[off] = (unsigned short)(ps >> 16);
    }
  }
}

// ---------- split-bf16 MFMA GEMM: C = A @ B^T + bias (r10-proven: 903 µs config) ----------
// B given as hi/lo ushort planes (rows x K); rows >= Nb are zero-staged. Stores
// guarded to col < Ns. Cols >= pc0 are stored as raw f32 into Pbuf (ld 48).
// NORM: blocks with col0 < 2048 L2-normalize each 64-col head-row before packing.
// Register prefetch + lgkm-only barriers: vmem spans the K-loop barriers.
template<bool A_PACKED, bool C_PACKED, bool NORM>
__global__ __launch_bounds__(256) void gemm_split(
    const void* __restrict__ Av, int lda,
    const unsigned short* __restrict__ Bhg,
    const unsigned short* __restrict__ Blg,
    const float* __restrict__ bias,
    void* __restrict__ Cv, float* __restrict__ Pbuf,
    int M, int ldc, int K, int Nb, int Ns, int pc0) {
  __shared__ unsigned short Ahi[128][40];
  __shared__ unsigned short Alo[128][40];
  __shared__ unsigned short Bhi[128][40];
  __shared__ unsigned short Blo[128][40];

  const int tid = threadIdx.x;
  const int row0 = blockIdx.y * 128;
  const int col0 = blockIdx.x * 128;
  const int wv = tid >> 6;
  const int l  = tid & 63;
  const int wr = wv >> 1, wc = wv & 1;
  const int lrow = l & 15;
  const int kgrp = (l >> 4) * 8;

  const int sr = tid >> 1;
  const int sk = (tid & 1) * 16;

  f32x4 acc[4][4];
#pragma unroll
  for (int i = 0; i < 4; i++)
#pragma unroll
    for (int j = 0; j < 4; j++) acc[i][j] = (f32x4){0.f, 0.f, 0.f, 0.f};

  uint4 pa[4];    // A_PACKED: 16 packed u32
  float4 pf[4];   // !A_PACKED: 16 floats
  uint4 pbh[2], pbl[2];   // B planes: 32B hi + 32B lo

  auto load_tile = [&](int k0) {
    if (A_PACKED) {
      const uint32_t* Ap = (const uint32_t*)Av + (size_t)(row0 + sr) * lda + k0 + sk;
#pragma unroll
      for (int i = 0; i < 4; i++) pa[i] = *(const uint4*)(Ap + i * 4);
    } else {
      const float* Ap = (const float*)Av + (size_t)(row0 + sr) * lda + k0 + sk;
#pragma unroll
      for (int i = 0; i < 4; i++) pf[i] = *(const float4*)(Ap + i * 4);
    }
    if (col0 + sr < Nb) {
      const unsigned short* bh = Bhg + (size_t)(col0 + sr) * K + k0 + sk;
      const unsigned short* bl = Blg + (size_t)(col0 + sr) * K + k0 + sk;
      pbh[0] = *(const uint4*)bh;  pbh[1] = *(const uint4*)(bh + 8);
      pbl[0] = *(const uint4*)bl;  pbl[1] = *(const uint4*)(bl + 8);
    } else {
      pbh[0] = pbh[1] = pbl[0] = pbl[1] = make_uint4(0u, 0u, 0u, 0u);
    }
  };

  auto commit_tile = [&]() {
    uint32_t hp[8], lp[8];
    if (A_PACKED) {
      uint32_t u[16];
#pragma unroll
      for (int i = 0; i < 4; i++) *(uint4*)&u[i * 4] = pa[i];
#pragma unroll
      for (int j = 0; j < 8; j++) {
        hp[j] = (u[2 * j] & 0xffffu) | (u[2 * j + 1] << 16);
        lp[j] = (u[2 * j] >> 16) | (u[2 * j + 1] & 0xffff0000u);
      }
    } else {
      float f[16];
#pragma unroll
      for (int i = 0; i < 4; i++) *(float4*)&f[i * 4] = pf[i];
      uint32_t uh[16], ulr[16];
#pragma unroll
      for (int j = 0; j < 16; j++) {
        uint32_t b = __float_as_uint(f[j]);
        uint32_t h = (b + 0x7fffu + ((b >> 16) & 1u)) >> 16;
        uh[j] = h;
        ulr[j] = __float_as_uint(f[j] - __uint_as_float(h << 16));
      }
#pragma unroll
      for (int j = 0; j < 8; j++) {
        hp[j] = uh[2 * j] | (uh[2 * j + 1] << 16);
        lp[j] = (ulr[2 * j] >> 16) | (ulr[2 * j + 1] & 0xffff0000u);
      }
    }
    *(uint4*)&Ahi[sr][sk]     = *(uint4*)&hp[0];
    *(uint4*)&Ahi[sr][sk + 8] = *(uint4*)&hp[4];
    *(uint4*)&Alo[sr][sk]     = *(uint4*)&lp[0];
    *(uint4*)&Alo[sr][sk + 8] = *(uint4*)&lp[4];
    // B: pure plane copies (no VALU transform)
    *(uint4*)&Bhi[sr][sk]     = pbh[0];
    *(uint4*)&Bhi[sr][sk + 8] = pbh[1];
    *(uint4*)&Blo[sr][sk]     = pbl[0];
    *(uint4*)&Blo[sr][sk + 8] = pbl[1];
  };

  load_tile(0);
  for (int k0 = 0; k0 < K; k0 += 32) {
    commit_tile();
    bar_lds();                               // flush ds_writes; vmem stays in flight
    if (k0 + 32 < K) load_tile(k0 + 32);     // spans the next barrier

    bf16x8 bh[4], bl[4];
#pragma unroll
    for (int j = 0; j < 4; j++) {
      bh[j] = *(const bf16x8*)&Bhi[wc * 64 + j * 16 + lrow][kgrp];
      bl[j] = *(const bf16x8*)&Blo[wc * 64 + j * 16 + lrow][kgrp];
    }
#pragma unroll
    for (int i = 0; i < 4; i++) {
      bf16x8 ah = *(const bf16x8*)&Ahi[wr * 64 + i * 16 + lrow][kgrp];
      bf16x8 al = *(const bf16x8*)&Alo[wr * 64 + i * 16 + lrow][kgrp];
#pragma unroll
      for (int j = 0; j < 4; j++) {
        acc[i][j] = __builtin_amdgcn_mfma_f32_16x16x32_bf16(ah, bh[j], acc[i][j], 0, 0, 0);
        acc[i][j] = __builtin_amdgcn_mfma_f32_16x16x32_bf16(ah, bl[j], acc[i][j], 0, 0, 0);
        acc[i][j] = __builtin_amdgcn_mfma_f32_16x16x32_bf16(al, bh[j], acc[i][j], 0, 0, 0);
      }
    }
    bar_lds();
  }

  // ---- epilogue: C/D layout col=lane&15, row=(lane>>4)*4+reg ----
  const int crow4 = (l >> 4) * 4;
  if (NORM && col0 < 2048) {
    // q/k rows: normalize each head-row (64 cols) in-register.
    float bj[4];
#pragma unroll
    for (int j = 0; j < 4; j++) bj[j] = bias[col0 + wc * 64 + j * 16 + lrow];
#pragma unroll
    for (int i = 0; i < 4; i++) {
#pragma unroll
      for (int r = 0; r < 4; r++) {
        float vals[4];
        float ss = 0.f;
#pragma unroll
        for (int j = 0; j < 4; j++) {
          vals[j] = acc[i][j][r] + bj[j];
          ss += vals[j] * vals[j];
        }
        ss = red16(ss);
        float sc = 1.f / fmaxf(sqrtf(ss), 1e-12f);
        const int rowb = row0 + wr * 64 + i * 16 + crow4 + r;
#pragma unroll
        for (int j = 0; j < 4; j++) {
          const int col = col0 + wc * 64 + j * 16 + lrow;
          ((uint32_t*)Cv)[(size_t)rowb * ldc + col] = pack_split(vals[j] * sc);
        }
      }
    }
  } else {
#pragma unroll
    for (int i = 0; i < 4; i++) {
#pragma unroll
      for (int j = 0; j < 4; j++) {
        const int col = col0 + wc * 64 + j * 16 + lrow;
        const float bv = (col < Ns) ? bias[col] : 0.f;
        const int rowb = row0 + wr * 64 + i * 16 + crow4;
#pragma unroll
        for (int r = 0; r < 4; r++) {
          float v = acc[i][j][r] + bv;
          if (col < Ns) {
            if (col >= pc0) {
              Pbuf[(size_t)(rowb + r) * 48 + (col - pc0)] = v;          // raw f32 params
            } else if (C_PACKED) {
              ((uint32_t*)Cv)[(size_t)(rowb + r) * ldc + col] = pack_split(v);
            } else {
              ((float*)Cv)[(size_t)(rowb + r) * ldc + col] = v;
            }
          }
        }
      }
    }
  }
}

// Titans recurrence — 2-barrier restructure of the proven 540-µs kernel.
// One block per (b,h), 512 threads = 8 waves x 8 S-rows; packed-fp32 (pk_fma);
// lgkm-only barriers. Steady-state chunk loop:
//   C: token scan[nt] -> partP; kh-partials[nt+1] (uses post-scan S) -> partK
//   bar
//   B: o-reduce/LN/store[nt] (reads partP) + kh-reduce/LN->dkh[nt+1] (reads partK,
//      independent DPP chains overlap) + commit tiles[nt+2] + prefetch[nt+3]
//   bar
// Tiles k/q/v double-buffered (committed 2 chunks ahead); partP/partK ping;
// dkh single-buffered (write-after-read across barrier).
__global__ __launch_bounds__(512) void titans_rec(
    uint32_t* __restrict__ qkv, const float* __restrict__ p,
    const float* __restrict__ w, const float* __restrict__ bparm) {
  const int bh = blockIdx.x;
  const int b = bh >> 4;
  const int h = bh & 15;
  const int tid = threadIdx.x;
  const int wv = tid >> 6;   // 0..7
  const int l = tid & 63;

  __shared__ float k_s[2][CSZ][DD];
  __shared__ float q_s[2][CSZ][DD];
  __shared__ float v_s[2][CSZ][DD];
  __shared__ float dkh_s[CSZ][DD];
  __shared__ float partP[WVS][CSZ][DD];   // po of chunk nt
  __shared__ float partK[WVS][CSZ][DD];   // kh partials of chunk nt+1
  __shared__ float4 prm_s[2][CSZ];

  f32x2 S2[4], M2[4];
#pragma unroll
  for (int r = 0; r < 4; r++) { S2[r] = (f32x2){0.f, 0.f}; M2[r] = (f32x2){0.f, 0.f}; }

  const float w_l = w[h * DD + l];
  const float b_l = bparm[h * DD + l];

  uint32_t* qbase = qkv + (size_t)(b * TT) * STR + h * DD;
  const float* pbase = p + (size_t)(b * TT) * 48 + h * 3;

  uint32_t rq[2], rk[2], rv[2];
  float rp0 = 0.f, rp1 = 0.f, rp2 = 0.f;

  // ---- prologue: commit tiles[0] and [1]; load regs[2]; dkh[0] from kh==0 ----
  {
#pragma unroll
    for (int cc = 0; cc < 2; cc++) {
#pragma unroll
      for (int i = 0; i < 2; i++) {
        const int row = wv + i * 8;
        size_t roff = (size_t)(cc * CSZ + row) * STR + l;
        q_s[cc][row][l] = unpack_f(qbase[roff]);
        k_s[cc][row][l] = unpack_f(qbase[roff + 1024]);
        v_s[cc][row][l] = unpack_f(qbase[roff + 2048]);
      }
      if (tid < CSZ) {
        const float* pp = pbase + (size_t)(cc * CSZ + tid) * 48;
        prm_s[cc][tid] = make_float4(sigmoidf_(pp[0]), sigmoidf_(pp[1]), sigmoidf_(pp[2]), 0.f);
      }
    }
#pragma unroll
    for (int i = 0; i < 2; i++) {
      size_t roff = (size_t)(2 * CSZ + wv + i * 8) * STR + l;
      rq[i] = qbase[roff];
      rk[i] = qbase[roff + 1024];
      rv[i] = qbase[roff + 2048];
    }
    if (tid < CSZ) {
      const float* pp = pbase + (size_t)(2 * CSZ + tid) * 48;
      rp0 = pp[0]; rp1 = pp[1]; rp2 = pp[2];
    }
  }
  bar_lds();
  // dkh[0]: S0 = 0 -> kh = 0 -> xhat = 0, y = b_l; c1 = 0.
  {
    const float rstd0 = rsqrtf(EPSF);
#pragma unroll
    for (int i = 0; i < 2; i++) {
      const int c = wv + i * 8;
      float dy = 2.f * (b_l - v_s[0][c][l]);
      float wdy = dy * w_l;
      float c2 = wave_sum(wdy) * (1.f / 64.f);
      dkh_s[c][l] = (wdy - c2) * rstd0;
    }
  }
  bar_lds();

  for (int nt = 0; nt < NTC; nt++) {
    const int buf = nt & 1;

    // ---- phase C: token scan[nt] -> partP; kh-partials[nt+1] -> partK ----
#pragma unroll
    for (int t = 0; t < CSZ; t++) {
      float4 prm = prm_s[buf][t];
      float a = prm.x * dkh_s[t][l];
      const f32x2 na2 = (f32x2){-a, -a};
      const f32x2 et2 = (f32x2){prm.z, prm.z};
      const f32x2 be2 = (f32x2){1.f - prm.y, 1.f - prm.y};
      const f32x2* kp2 = (const f32x2*)&k_s[buf][t][wv * 8];
      const f32x2* qp2 = (const f32x2*)&q_s[buf][t][wv * 8];
      f32x2 po2 = (f32x2){0.f, 0.f};
#pragma unroll
      for (int pq = 0; pq < 4; pq++) {
        M2[pq] = et2 * M2[pq] + na2 * kp2[pq];   // pk_mul + pk_fma
        S2[pq] = be2 * S2[pq] + M2[pq];          // pk_fma
        po2    = qp2[pq] * S2[pq] + po2;         // pk_fma
      }
      partP[wv][t][l] = po2.x + po2.y;
    }
    if (nt + 1 < NTC) {
#pragma unroll
      for (int c = 0; c < CSZ; c++) {
        const f32x2* kp2 = (const f32x2*)&k_s[buf ^ 1][c][wv * 8];
        f32x2 a2;
        a2 = kp2[0] * S2[0];
        a2 = kp2[1] * S2[1] + a2;
        a2 = kp2[2] * S2[2] + a2;
        a2 = kp2[3] * S2[3] + a2;
        partK[wv][c][l] = a2.x + a2.y;
      }
    }
    bar_lds();

    // ---- phase B: o-store[nt]; dkh[nt+1]; commit[nt+2]; prefetch[nt+3] ----
#pragma unroll
    for (int i = 0; i < 2; i++) {
      const int t = wv + i * 8;
      float o = 0.f;
#pragma unroll
      for (int ww = 0; ww < WVS; ww++) o += partP[ww][t][l];
      float mu = wave_sum(o) * (1.f / 64.f);
      float xc = o - mu;
      float var = wave_sum(xc * xc) * (1.f / 64.f);
      float rstd = rsqrtf(var + EPSF);
      float y = xc * rstd * w_l + b_l;
      qbase[(size_t)(nt * CSZ + t) * STR + 2048 + l] = pack_split(y);
    }
    if (nt + 1 < NTC) {
#pragma unroll
      for (int i = 0; i < 2; i++) {
        const int c = wv + i * 8;
        float kh = 0.f;
#pragma unroll
        for (int ww = 0; ww < WVS; ww++) kh += partK[ww][c][l];
        float mu = wave_sum(kh) * (1.f / 64.f);
        float xc = kh - mu;
        float var = wave_sum(xc * xc) * (1.f / 64.f);
        float rstd = rsqrtf(var + EPSF);
        float xhat = xc * rstd;
        float y = xhat * w_l + b_l;
        float dy = 2.f * (y - v_s[buf ^ 1][c][l]);
        float wdy = dy * w_l;
        float c1 = wave_sum(xhat * wdy) * (1.f / 64.f);
        float c2 = wave_sum(wdy) * (1.f / 64.f);
        dkh_s[c][l] = (wdy - xhat * c1 - c2) * rstd;
      }
    }
    if (nt + 2 < NTC) {
#pragma unroll
      for (int i = 0; i < 2; i++) {
        const int row = wv + i * 8;
        k_s[buf][row][l] = unpack_f(rk[i]);
        q_s[buf][row][l] = unpack_f(rq[i]);
        v_s[buf][row][l] = unpack_f(rv[i]);
      }
      if (tid < CSZ)
        prm_s[buf][tid] = make_float4(sigmoidf_(rp0), sigmoidf_(rp1), sigmoidf_(rp2), 0.f);
    }
    if (nt + 3 < NTC) {
#pragma unroll
      for (int i = 0; i < 2; i++) {
        size_t roff = (size_t)((nt + 3) * CSZ + wv + i * 8) * STR + l;
        rq[i] = qbase[roff];
        rk[i] = qbase[roff + 1024];
        rv[i] = qbase[roff + 2048];
      }
      if (tid < CSZ) {
        const float* pp = pbase + (size_t)((nt + 3) * CSZ + tid) * 48;
        rp0 = pp[0]; rp1 = pp[1]; rp2 = pp[2];
      }
    }
    bar_lds();
  }
}

extern "C" void kernel_launch(void* const* d_in, const int* in_sizes, int n_in,
                              void* d_out, int out_size, void* d_ws, size_t ws_size,
                              hipStream_t stream) {
  const float* x      = (const float*)d_in[0];
  const float* W_attn = (const float*)d_in[1];
  const float* b_attn = (const float*)d_in[2];
  const float* W_parm = (const float*)d_in[3];
  const float* b_parm = (const float*)d_in[4];
  const float* W_proj = (const float*)d_in[5];
  const float* b_proj = (const float*)d_in[6];
  const float* w      = (const float*)d_in[7];
  const float* bb     = (const float*)d_in[8];
  float* out = (float*)d_out;

  const int M = BB * TT;        // 8192
  uint32_t* qkv = (uint32_t*)d_ws;                           // M x 3072 packed u32 (aligned rows)
  float* pbf = (float*)(qkv + (size_t)M * STR);              // M x 48 f32 (compact params)
  unsigned short* wattn_hi = (unsigned short*)(pbf + (size_t)M * 48);   // 3120 x 1024
  unsigned short* wattn_lo = wattn_hi + (size_t)3120 * 1024;
  unsigned short* wproj_hi = wattn_lo + (size_t)3120 * 1024;            // 1024 x 1024
  unsigned short* wproj_lo = wproj_hi + (size_t)1024 * 1024;
  float* bcat = (float*)(wproj_lo + (size_t)1024 * 1024);               // 3120 f32

  hipMemcpyAsync(bcat, b_attn, 3072 * sizeof(float), hipMemcpyDeviceToDevice, stream);
  hipMemcpyAsync(bcat + 3072, b_parm, 48 * sizeof(float), hipMemcpyDeviceToDevice, stream);

  // pre-split + transpose weights into hi/lo planes (one-time, memory-bound)
  split_transpose_pl<<<dim3(3072 / 32, 1024 / 32), 256, 0, stream>>>(W_attn, wattn_hi, wattn_lo, 1024, 3072, 0);
  split_transpose_pl<<<dim3(2, 1024 / 32), 256, 0, stream>>>(W_parm, wattn_hi, wattn_lo, 1024, 48, 3072);
  split_transpose_pl<<<dim3(1024 / 32, 1024 / 32), 256, 0, stream>>>(W_proj, wproj_hi, wproj_lo, 1024, 1024, 0);

  // fused: [qkv | p] = x @ [W_attn | W_param] + bias; q/k L2-normalized in-epilogue;
  // q/k/v packed into qkv, p raw f32 into pbf.
  gemm_split<false, true, true><<<dim3(25, M / 128), 256, 0, stream>>>(
      x, CCH, wattn_hi, wattn_lo, bcat, qkv, pbf, M, STR, CCH,
      /*Nb=*/3120, /*Ns=*/3120, /*pc0=*/3072);
  // recurrence; writes packed LN(o) into v-slot
  titans_rec<<<BB * HH, 512, 0, stream>>>(qkv, pbf, w, bb);
  // out = o @ W_proj + b_proj
  gemm_split<true, false, false><<<dim3(CCH / 128, M / 128), 256, 0, stream>>>(
      qkv + 2048, STR, wproj_hi, wproj_lo, b_proj, out, nullptr, M, CCH, CCH,
      /*Nb=*/1024, /*Ns=*/1024, /*pc0=*/1 << 30);
}

// Round 13
// 892.694 us; speedup vs baseline: 1.3459x; 1.0179x over previous
//
#include <hip/hip_runtime.h>
#include <cstddef>
#include <cstdint>
#include <math.h>

#define BB   4
#define TT   2048
#define CCH  1024
#define HH   16
#define DD   64
#define CSZ  16
#define NTC  128
#define EPSF 1e-5f
#define WVS  8
#define STR  3072   // qkv row stride (u32): q[0,1024) k[1024,2048) v[2048,3072); p separate

typedef __attribute__((ext_vector_type(8))) short bf16x8;
typedef __attribute__((ext_vector_type(4))) float f32x4;
typedef __attribute__((ext_vector_type(2))) float f32x2;

// Barrier that flushes LDS ops only. Global stores / register prefetch loads stay
// in flight across the barrier (guide T4); compiler still inserts vmcnt(N) before
// each use of a prefetched register.
__device__ __forceinline__ void bar_lds() {
  asm volatile("s_waitcnt lgkmcnt(0)" ::: "memory");
  __builtin_amdgcn_s_barrier();
}

// ---------- split-float helpers: f32 ≈ hi(bf16) + lo(bf16), packed (hi | lo<<16) ----------
__device__ __forceinline__ uint32_t pack_split(float f) {
  uint32_t b = __float_as_uint(f);
  uint32_t uh = (b + 0x7fffu + ((b >> 16) & 1u)) >> 16;   // RNE bf16 of f
  float fh = __uint_as_float(uh << 16);
  float r = f - fh;
  return uh | (__float_as_uint(r) & 0xffff0000u);          // lo = trunc bf16 of residual
}
__device__ __forceinline__ float unpack_f(uint32_t u) {
  return __uint_as_float(u << 16) + __uint_as_float(u & 0xffff0000u);
}

// Wave64 sum via DPP (VALU pipe).
__device__ __forceinline__ float wave_sum(float x) {
  float v = x;
  v += __int_as_float(__builtin_amdgcn_update_dpp(0, __float_as_int(v), 0x111, 0xf, 0xf, true));
  v += __int_as_float(__builtin_amdgcn_update_dpp(0, __float_as_int(v), 0x112, 0xf, 0xf, true));
  v += __int_as_float(__builtin_amdgcn_update_dpp(0, __float_as_int(v), 0x114, 0xf, 0xf, true));
  v += __int_as_float(__builtin_amdgcn_update_dpp(0, __float_as_int(v), 0x118, 0xf, 0xf, true));
  v += __int_as_float(__builtin_amdgcn_update_dpp(0, __float_as_int(v), 0x142, 0xa, 0xf, true));
  v += __int_as_float(__builtin_amdgcn_update_dpp(0, __float_as_int(v), 0x143, 0xc, 0xf, true));
  return __int_as_float(__builtin_amdgcn_readlane(__float_as_int(v), 63));
}

// Sum across a 16-lane group: quad_perm xor1, xor2, row_ror:4, row_ror:8.
__device__ __forceinline__ float red16(float x) {
  float v = x;
  v += __int_as_float(__builtin_amdgcn_update_dpp(0, __float_as_int(v), 0x0B1, 0xf, 0xf, true));
  v += __int_as_float(__builtin_amdgcn_update_dpp(0, __float_as_int(v), 0x04E, 0xf, 0xf, true));
  v += __int_as_float(__builtin_amdgcn_update_dpp(0, __float_as_int(v), 0x124, 0xf, 0xf, true));
  v += __int_as_float(__builtin_amdgcn_update_dpp(0, __float_as_int(v), 0x128, 0xf, 0xf, true));
  return v;
}

__device__ __forceinline__ float sigmoidf_(float x) {
  return 1.f / (1.f + expf(-x));
}

// ---------- transpose + split into PLANES: W (KxN f32) -> Whi/Wlo rows [rowOff, rowOff+N) ----------
__global__ __launch_bounds__(256) void split_transpose_pl(
    const float* __restrict__ W, unsigned short* __restrict__ Whi,
    unsigned short* __restrict__ Wlo, int K, int N, int rowOff) {
  __shared__ float t[32][33];
  const int n0 = blockIdx.x * 32, k0 = blockIdx.y * 32;
  const int tx = threadIdx.x & 31, ty = threadIdx.x >> 5;  // ty 0..7
#pragma unroll
  for (int i = 0; i < 4; i++) {
    int n = n0 + tx;
    t[ty + i * 8][tx] = (n < N) ? W[(size_t)(k0 + ty + i * 8) * N + n] : 0.f;
  }
  __syncthreads();
#pragma unroll
  for (int i = 0; i < 4; i++) {
    int n = n0 + ty + i * 8;
    if (n < N) {
      uint32_t ps = pack_split(t[tx][ty + i * 8]);
      size_t off = (size_t)(rowOff + n) * K + k0 + tx;
      Whi[off] = (unsigned short)(ps & 0xffffu);
      Wlo[off] = (unsigned short)(ps >> 16);
    }
  }
}

// ---------- split-bf16 MFMA GEMM: C = A @ B^T + bias (r10-proven: 903 µs config) ----------
template<bool A_PACKED, bool C_PACKED, bool NORM>
__global__ __launch_bounds__(256) void gemm_split(
    const void* __restrict__ Av, int lda,
    const unsigned short* __restrict__ Bhg,
    const unsigned short* __restrict__ Blg,
    const float* __restrict__ bias,
    void* __restrict__ Cv, float* __restrict__ Pbuf,
    int M, int ldc, int K, int Nb, int Ns, int pc0) {
  __shared__ unsigned short Ahi[128][40];
  __shared__ unsigned short Alo[128][40];
  __shared__ unsigned short Bhi[128][40];
  __shared__ unsigned short Blo[128][40];

  const int tid = threadIdx.x;
  const int row0 = blockIdx.y * 128;
  const int col0 = blockIdx.x * 128;
  const int wv = tid >> 6;
  const int l  = tid & 63;
  const int wr = wv >> 1, wc = wv & 1;
  const int lrow = l & 15;
  const int kgrp = (l >> 4) * 8;

  const int sr = tid >> 1;
  const int sk = (tid & 1) * 16;

  f32x4 acc[4][4];
#pragma unroll
  for (int i = 0; i < 4; i++)
#pragma unroll
    for (int j = 0; j < 4; j++) acc[i][j] = (f32x4){0.f, 0.f, 0.f, 0.f};

  uint4 pa[4];    // A_PACKED: 16 packed u32
  float4 pf[4];   // !A_PACKED: 16 floats
  uint4 pbh[2], pbl[2];   // B planes: 32B hi + 32B lo

  auto load_tile = [&](int k0) {
    if (A_PACKED) {
      const uint32_t* Ap = (const uint32_t*)Av + (size_t)(row0 + sr) * lda + k0 + sk;
#pragma unroll
      for (int i = 0; i < 4; i++) pa[i] = *(const uint4*)(Ap + i * 4);
    } else {
      const float* Ap = (const float*)Av + (size_t)(row0 + sr) * lda + k0 + sk;
#pragma unroll
      for (int i = 0; i < 4; i++) pf[i] = *(const float4*)(Ap + i * 4);
    }
    if (col0 + sr < Nb) {
      const unsigned short* bh = Bhg + (size_t)(col0 + sr) * K + k0 + sk;
      const unsigned short* bl = Blg + (size_t)(col0 + sr) * K + k0 + sk;
      pbh[0] = *(const uint4*)bh;  pbh[1] = *(const uint4*)(bh + 8);
      pbl[0] = *(const uint4*)bl;  pbl[1] = *(const uint4*)(bl + 8);
    } else {
      pbh[0] = pbh[1] = pbl[0] = pbl[1] = make_uint4(0u, 0u, 0u, 0u);
    }
  };

  auto commit_tile = [&]() {
    uint32_t hp[8], lp[8];
    if (A_PACKED) {
      uint32_t u[16];
#pragma unroll
      for (int i = 0; i < 4; i++) *(uint4*)&u[i * 4] = pa[i];
#pragma unroll
      for (int j = 0; j < 8; j++) {
        hp[j] = (u[2 * j] & 0xffffu) | (u[2 * j + 1] << 16);
        lp[j] = (u[2 * j] >> 16) | (u[2 * j + 1] & 0xffff0000u);
      }
    } else {
      float f[16];
#pragma unroll
      for (int i = 0; i < 4; i++) *(float4*)&f[i * 4] = pf[i];
      uint32_t uh[16], ulr[16];
#pragma unroll
      for (int j = 0; j < 16; j++) {
        uint32_t b = __float_as_uint(f[j]);
        uint32_t h = (b + 0x7fffu + ((b >> 16) & 1u)) >> 16;
        uh[j] = h;
        ulr[j] = __float_as_uint(f[j] - __uint_as_float(h << 16));
      }
#pragma unroll
      for (int j = 0; j < 8; j++) {
        hp[j] = uh[2 * j] | (uh[2 * j + 1] << 16);
        lp[j] = (ulr[2 * j] >> 16) | (ulr[2 * j + 1] & 0xffff0000u);
      }
    }
    *(uint4*)&Ahi[sr][sk]     = *(uint4*)&hp[0];
    *(uint4*)&Ahi[sr][sk + 8] = *(uint4*)&hp[4];
    *(uint4*)&Alo[sr][sk]     = *(uint4*)&lp[0];
    *(uint4*)&Alo[sr][sk + 8] = *(uint4*)&lp[4];
    // B: pure plane copies (no VALU transform)
    *(uint4*)&Bhi[sr][sk]     = pbh[0];
    *(uint4*)&Bhi[sr][sk + 8] = pbh[1];
    *(uint4*)&Blo[sr][sk]     = pbl[0];
    *(uint4*)&Blo[sr][sk + 8] = pbl[1];
  };

  load_tile(0);
  for (int k0 = 0; k0 < K; k0 += 32) {
    commit_tile();
    bar_lds();                               // flush ds_writes; vmem stays in flight
    if (k0 + 32 < K) load_tile(k0 + 32);     // spans the next barrier

    bf16x8 bh[4], bl[4];
#pragma unroll
    for (int j = 0; j < 4; j++) {
      bh[j] = *(const bf16x8*)&Bhi[wc * 64 + j * 16 + lrow][kgrp];
      bl[j] = *(const bf16x8*)&Blo[wc * 64 + j * 16 + lrow][kgrp];
    }
#pragma unroll
    for (int i = 0; i < 4; i++) {
      bf16x8 ah = *(const bf16x8*)&Ahi[wr * 64 + i * 16 + lrow][kgrp];
      bf16x8 al = *(const bf16x8*)&Alo[wr * 64 + i * 16 + lrow][kgrp];
#pragma unroll
      for (int j = 0; j < 4; j++) {
        acc[i][j] = __builtin_amdgcn_mfma_f32_16x16x32_bf16(ah, bh[j], acc[i][j], 0, 0, 0);
        acc[i][j] = __builtin_amdgcn_mfma_f32_16x16x32_bf16(ah, bl[j], acc[i][j], 0, 0, 0);
        acc[i][j] = __builtin_amdgcn_mfma_f32_16x16x32_bf16(al, bh[j], acc[i][j], 0, 0, 0);
      }
    }
    bar_lds();
  }

  // ---- epilogue: C/D layout col=lane&15, row=(lane>>4)*4+reg ----
  const int crow4 = (l >> 4) * 4;
  if (NORM && col0 < 2048) {
    // q/k rows: normalize each head-row (64 cols) in-register.
    float bj[4];
#pragma unroll
    for (int j = 0; j < 4; j++) bj[j] = bias[col0 + wc * 64 + j * 16 + lrow];
#pragma unroll
    for (int i = 0; i < 4; i++) {
#pragma unroll
      for (int r = 0; r < 4; r++) {
        float vals[4];
        float ss = 0.f;
#pragma unroll
        for (int j = 0; j < 4; j++) {
          vals[j] = acc[i][j][r] + bj[j];
          ss += vals[j] * vals[j];
        }
        ss = red16(ss);
        float sc = 1.f / fmaxf(sqrtf(ss), 1e-12f);
        const int rowb = row0 + wr * 64 + i * 16 + crow4 + r;
#pragma unroll
        for (int j = 0; j < 4; j++) {
          const int col = col0 + wc * 64 + j * 16 + lrow;
          ((uint32_t*)Cv)[(size_t)rowb * ldc + col] = pack_split(vals[j] * sc);
        }
      }
    }
  } else {
#pragma unroll
    for (int i = 0; i < 4; i++) {
#pragma unroll
      for (int j = 0; j < 4; j++) {
        const int col = col0 + wc * 64 + j * 16 + lrow;
        const float bv = (col < Ns) ? bias[col] : 0.f;
        const int rowb = row0 + wr * 64 + i * 16 + crow4;
#pragma unroll
        for (int r = 0; r < 4; r++) {
          float v = acc[i][j][r] + bv;
          if (col < Ns) {
            if (col >= pc0) {
              Pbuf[(size_t)(rowb + r) * 48 + (col - pc0)] = v;          // raw f32 params
            } else if (C_PACKED) {
              ((uint32_t*)Cv)[(size_t)(rowb + r) * ldc + col] = pack_split(v);
            } else {
              ((float*)Cv)[(size_t)(rowb + r) * ldc + col] = v;
            }
          }
        }
      }
    }
  }
}

// Titans recurrence — r12 2-barrier structure with ONE change: phase-C k/q LDS
// reads issued as explicit b128 (f32x4) and split to f32x2 pairs in registers
// (shufflevector = register renaming, pk math unchanged). Tests whether the
// compiler was emitting ds_read_b64s for the f32x2 pointer walks (the dominant
// DS-pipe term, ~88% pipe occupancy by count).
__global__ __launch_bounds__(512) void titans_rec(
    uint32_t* __restrict__ qkv, const float* __restrict__ p,
    const float* __restrict__ w, const float* __restrict__ bparm) {
  const int bh = blockIdx.x;
  const int b = bh >> 4;
  const int h = bh & 15;
  const int tid = threadIdx.x;
  const int wv = tid >> 6;   // 0..7
  const int l = tid & 63;

  __shared__ float k_s[2][CSZ][DD];
  __shared__ float q_s[2][CSZ][DD];
  __shared__ float v_s[2][CSZ][DD];
  __shared__ float dkh_s[CSZ][DD];
  __shared__ float partP[WVS][CSZ][DD];   // po of chunk nt
  __shared__ float partK[WVS][CSZ][DD];   // kh partials of chunk nt+1
  __shared__ float4 prm_s[2][CSZ];

  f32x2 S2[4], M2[4];
#pragma unroll
  for (int r = 0; r < 4; r++) { S2[r] = (f32x2){0.f, 0.f}; M2[r] = (f32x2){0.f, 0.f}; }

  const float w_l = w[h * DD + l];
  const float b_l = bparm[h * DD + l];

  uint32_t* qbase = qkv + (size_t)(b * TT) * STR + h * DD;
  const float* pbase = p + (size_t)(b * TT) * 48 + h * 3;

  uint32_t rq[2], rk[2], rv[2];
  float rp0 = 0.f, rp1 = 0.f, rp2 = 0.f;

  // ---- prologue: commit tiles[0] and [1]; load regs[2]; dkh[0] from kh==0 ----
  {
#pragma unroll
    for (int cc = 0; cc < 2; cc++) {
#pragma unroll
      for (int i = 0; i < 2; i++) {
        const int row = wv + i * 8;
        size_t roff = (size_t)(cc * CSZ + row) * STR + l;
        q_s[cc][row][l] = unpack_f(qbase[roff]);
        k_s[cc][row][l] = unpack_f(qbase[roff + 1024]);
        v_s[cc][row][l] = unpack_f(qbase[roff + 2048]);
      }
      if (tid < CSZ) {
        const float* pp = pbase + (size_t)(cc * CSZ + tid) * 48;
        prm_s[cc][tid] = make_float4(sigmoidf_(pp[0]), sigmoidf_(pp[1]), sigmoidf_(pp[2]), 0.f);
      }
    }
#pragma unroll
    for (int i = 0; i < 2; i++) {
      size_t roff = (size_t)(2 * CSZ + wv + i * 8) * STR + l;
      rq[i] = qbase[roff];
      rk[i] = qbase[roff + 1024];
      rv[i] = qbase[roff + 2048];
    }
    if (tid < CSZ) {
      const float* pp = pbase + (size_t)(2 * CSZ + tid) * 48;
      rp0 = pp[0]; rp1 = pp[1]; rp2 = pp[2];
    }
  }
  bar_lds();
  // dkh[0]: S0 = 0 -> kh = 0 -> xhat = 0, y = b_l; c1 = 0.
  {
    const float rstd0 = rsqrtf(EPSF);
#pragma unroll
    for (int i = 0; i < 2; i++) {
      const int c = wv + i * 8;
      float dy = 2.f * (b_l - v_s[0][c][l]);
      float wdy = dy * w_l;
      float c2 = wave_sum(wdy) * (1.f / 64.f);
      dkh_s[c][l] = (wdy - c2) * rstd0;
    }
  }
  bar_lds();

  for (int nt = 0; nt < NTC; nt++) {
    const int buf = nt & 1;

    // ---- phase C: token scan[nt] -> partP; kh-partials[nt+1] -> partK ----
#pragma unroll
    for (int t = 0; t < CSZ; t++) {
      float4 prm = prm_s[buf][t];
      float a = prm.x * dkh_s[t][l];
      const f32x2 na2 = (f32x2){-a, -a};
      const f32x2 et2 = (f32x2){prm.z, prm.z};
      const f32x2 be2 = (f32x2){1.f - prm.y, 1.f - prm.y};
      f32x4 kv0 = *(const f32x4*)&k_s[buf][t][wv * 8];       // ds_read_b128
      f32x4 kv1 = *(const f32x4*)&k_s[buf][t][wv * 8 + 4];   // ds_read_b128
      f32x4 qv0 = *(const f32x4*)&q_s[buf][t][wv * 8];
      f32x4 qv1 = *(const f32x4*)&q_s[buf][t][wv * 8 + 4];
      f32x2 kp[4], qp[4];
      kp[0] = __builtin_shufflevector(kv0, kv0, 0, 1);
      kp[1] = __builtin_shufflevector(kv0, kv0, 2, 3);
      kp[2] = __builtin_shufflevector(kv1, kv1, 0, 1);
      kp[3] = __builtin_shufflevector(kv1, kv1, 2, 3);
      qp[0] = __builtin_shufflevector(qv0, qv0, 0, 1);
      qp[1] = __builtin_shufflevector(qv0, qv0, 2, 3);
      qp[2] = __builtin_shufflevector(qv1, qv1, 0, 1);
      qp[3] = __builtin_shufflevector(qv1, qv1, 2, 3);
      f32x2 po2 = (f32x2){0.f, 0.f};
#pragma unroll
      for (int pq = 0; pq < 4; pq++) {
        M2[pq] = et2 * M2[pq] + na2 * kp[pq];   // pk_mul + pk_fma
        S2[pq] = be2 * S2[pq] + M2[pq];         // pk_fma
        po2    = qp[pq] * S2[pq] + po2;         // pk_fma
      }
      partP[wv][t][l] = po2.x + po2.y;
    }
    if (nt + 1 < NTC) {
#pragma unroll
      for (int c = 0; c < CSZ; c++) {
        f32x4 kv0 = *(const f32x4*)&k_s[buf ^ 1][c][wv * 8];     // ds_read_b128
        f32x4 kv1 = *(const f32x4*)&k_s[buf ^ 1][c][wv * 8 + 4];
        f32x2 a2;
        a2 = __builtin_shufflevector(kv0, kv0, 0, 1) * S2[0];
        a2 = __builtin_shufflevector(kv0, kv0, 2, 3) * S2[1] + a2;
        a2 = __builtin_shufflevector(kv1, kv1, 0, 1) * S2[2] + a2;
        a2 = __builtin_shufflevector(kv1, kv1, 2, 3) * S2[3] + a2;
        partK[wv][c][l] = a2.x + a2.y;
      }
    }
    bar_lds();

    // ---- phase B: o-store[nt]; dkh[nt+1]; commit[nt+2]; prefetch[nt+3] ----
#pragma unroll
    for (int i = 0; i < 2; i++) {
      const int t = wv + i * 8;
      float o = 0.f;
#pragma unroll
      for (int ww = 0; ww < WVS; ww++) o += partP[ww][t][l];
      float mu = wave_sum(o) * (1.f / 64.f);
      float xc = o - mu;
      float var = wave_sum(xc * xc) * (1.f / 64.f);
      float rstd = rsqrtf(var + EPSF);
      float y = xc * rstd * w_l + b_l;
      qbase[(size_t)(nt * CSZ + t) * STR + 2048 + l] = pack_split(y);
    }
    if (nt + 1 < NTC) {
#pragma unroll
      for (int i = 0; i < 2; i++) {
        const int c = wv + i * 8;
        float kh = 0.f;
#pragma unroll
        for (int ww = 0; ww < WVS; ww++) kh += partK[ww][c][l];
        float mu = wave_sum(kh) * (1.f / 64.f);
        float xc = kh - mu;
        float var = wave_sum(xc * xc) * (1.f / 64.f);
        float rstd = rsqrtf(var + EPSF);
        float xhat = xc * rstd;
        float y = xhat * w_l + b_l;
        float dy = 2.f * (y - v_s[buf ^ 1][c][l]);
        float wdy = dy * w_l;
        float c1 = wave_sum(xhat * wdy) * (1.f / 64.f);
        float c2 = wave_sum(wdy) * (1.f / 64.f);
        dkh_s[c][l] = (wdy - xhat * c1 - c2) * rstd;
      }
    }
    if (nt + 2 < NTC) {
#pragma unroll
      for (int i = 0; i < 2; i++) {
        const int row = wv + i * 8;
        k_s[buf][row][l] = unpack_f(rk[i]);
        q_s[buf][row][l] = unpack_f(rq[i]);
        v_s[buf][row][l] = unpack_f(rv[i]);
      }
      if (tid < CSZ)
        prm_s[buf][tid] = make_float4(sigmoidf_(rp0), sigmoidf_(rp1), sigmoidf_(rp2), 0.f);
    }
    if (nt + 3 < NTC) {
#pragma unroll
      for (int i = 0; i < 2; i++) {
        size_t roff = (size_t)((nt + 3) * CSZ + wv + i * 8) * STR + l;
        rq[i] = qbase[roff];
        rk[i] = qbase[roff + 1024];
        rv[i] = qbase[roff + 2048];
      }
      if (tid < CSZ) {
        const float* pp = pbase + (size_t)((nt + 3) * CSZ + tid) * 48;
        rp0 = pp[0]; rp1 = pp[1]; rp2 = pp[2];
      }
    }
    bar_lds();
  }
}

extern "C" void kernel_launch(void* const* d_in, const int* in_sizes, int n_in,
                              void* d_out, int out_size, void* d_ws, size_t ws_size,
                              hipStream_t stream) {
  const float* x      = (const float*)d_in[0];
  const float* W_attn = (const float*)d_in[1];
  const float* b_attn = (const float*)d_in[2];
  const float* W_parm = (const float*)d_in[3];
  const float* b_parm = (const float*)d_in[4];
  const float* W_proj = (const float*)d_in[5];
  const float* b_proj = (const float*)d_in[6];
  const float* w      = (const float*)d_in[7];
  const float* bb     = (const float*)d_in[8];
  float* out = (float*)d_out;

  const int M = BB * TT;        // 8192
  uint32_t* qkv = (uint32_t*)d_ws;                           // M x 3072 packed u32 (aligned rows)
  float* pbf = (float*)(qkv + (size_t)M * STR);              // M x 48 f32 (compact params)
  unsigned short* wattn_hi = (unsigned short*)(pbf + (size_t)M * 48);   // 3120 x 1024
  unsigned short* wattn_lo = wattn_hi + (size_t)3120 * 1024;
  unsigned short* wproj_hi = wattn_lo + (size_t)3120 * 1024;            // 1024 x 1024
  unsigned short* wproj_lo = wproj_hi + (size_t)1024 * 1024;
  float* bcat = (float*)(wproj_lo + (size_t)1024 * 1024);               // 3120 f32

  hipMemcpyAsync(bcat, b_attn, 3072 * sizeof(float), hipMemcpyDeviceToDevice, stream);
  hipMemcpyAsync(bcat + 3072, b_parm, 48 * sizeof(float), hipMemcpyDeviceToDevice, stream);

  // pre-split + transpose weights into hi/lo planes (one-time, memory-bound)
  split_transpose_pl<<<dim3(3072 / 32, 1024 / 32), 256, 0, stream>>>(W_attn, wattn_hi, wattn_lo, 1024, 3072, 0);
  split_transpose_pl<<<dim3(2, 1024 / 32), 256, 0, stream>>>(W_parm, wattn_hi, wattn_lo, 1024, 48, 3072);
  split_transpose_pl<<<dim3(1024 / 32, 1024 / 32), 256, 0, stream>>>(W_proj, wproj_hi, wproj_lo, 1024, 1024, 0);

  // fused: [qkv | p] = x @ [W_attn | W_param] + bias; q/k L2-normalized in-epilogue;
  // q/k/v packed into qkv, p raw f32 into pbf.
  gemm_split<false, true, true><<<dim3(25, M / 128), 256, 0, stream>>>(
      x, CCH, wattn_hi, wattn_lo, bcat, qkv, pbf, M, STR, CCH,
      /*Nb=*/3120, /*Ns=*/3120, /*pc0=*/3072);
  // recurrence; writes packed LN(o) into v-slot
  titans_rec<<<BB * HH, 512, 0, stream>>>(qkv, pbf, w, bb);
  // out = o @ W_proj + b_proj
  gemm_split<true, false, false><<<dim3(CCH / 128, M / 128), 256, 0, stream>>>(
      qkv + 2048, STR, wproj_hi, wproj_lo, b_proj, out, nullptr, M, CCH, CCH,
      /*Nb=*/1024, /*Ns=*/1024, /*pc0=*/1 << 30);
}